// Round 9
// baseline (89.889 us; speedup 1.0000x reference)
//
#include <hip/hip_runtime.h>
#include <math.h>

#define B_  64
#define VL 256
#define TL 512
#define HD 512
#define KV 127   // (VL-1)/2
#define KT 255   // (TL-1)/2
#define EPSF 1e-8f

typedef __attribute__((ext_vector_type(8))) short short8;
typedef __attribute__((ext_vector_type(4))) float f32x4;

// workspace layout in 4-byte elements (no init needed: every slot written each call)
#define WS_ROWP  0                       // B_*4*VL u32 partial row maxes (per n-tile)
#define WS_COLP  (B_*4*VL)               // B_*2*TL u32 partial col maxes (per m-tile)
#define WS_SRC   (WS_COLP + B_*2*TL)     // B_*768 i32 gather sources

__device__ __forceinline__ unsigned fkey(float f) {
    unsigned u = __float_as_uint(f);
    return (u & 0x80000000u) ? ~u : (u | 0x80000000u);  // order-preserving float->uint
}

__device__ __forceinline__ unsigned cvt_pk_bf16(float a, float b) {
    unsigned r;
    asm("v_cvt_pk_bf16_f32 %0, %1, %2" : "=v"(r) : "v"(a), "v"(b));
    return r;   // {bf16(a) lo, bf16(b) hi}, RNE
}

// trunc-split one pair: hh = {a.hi16,b.hi16}, ll = {bf16(a-ah), bf16(b-bh)}
__device__ __forceinline__ void split_pair(float a, float b, unsigned& hh, unsigned& ll, float& ss) {
    ss = fmaf(a, a, ss);
    ss = fmaf(b, b, ss);
    unsigned ua = __float_as_uint(a) & 0xFFFF0000u;
    unsigned ub = __float_as_uint(b) & 0xFFFF0000u;
    hh = __builtin_amdgcn_perm(ub, ua, 0x07060302u);
    ll = cvt_pk_bf16(a - __uint_as_float(ua), b - __uint_as_float(ub));
}

// stage 8 f32 -> h/l planes (uint4 each)
__device__ __forceinline__ void cvt_store8(unsigned* __restrict__ ph, unsigned* __restrict__ pl,
                                           float4 x0, float4 x1, float& ss) {
    unsigned hh0, hh1, hh2, hh3, ll0, ll1, ll2, ll3;
    split_pair(x0.x, x0.y, hh0, ll0, ss);
    split_pair(x0.z, x0.w, hh1, ll1, ss);
    split_pair(x1.x, x1.y, hh2, ll2, ss);
    split_pair(x1.z, x1.w, hh3, ll3, ss);
    *(uint4*)ph = (uint4){hh0, hh1, hh2, hh3};
    *(uint4*)pl = (uint4){ll0, ll1, ll2, ll3};
}

// per-batch 128x128 tile, K=512, 4 waves of 64x64, 2 blocks/CU:
// split-bf16 3-pass MFMA, dbuf LDS (64KB), chunk-XOR swizzle
__global__ __launch_bounds__(256, 2) void k_simmax(const float* __restrict__ video,
                                                   const float* __restrict__ text,
                                                   unsigned* __restrict__ rowp,
                                                   unsigned* __restrict__ colp) {
    __shared__ __align__(16) unsigned pA[2][2][2048];   // [buf][h/l][128 rows x 16 uints]
    __shared__ __align__(16) unsigned pB[2][2][2048];
    __shared__ float vns_s[128], tns_s[128];
    __shared__ unsigned rowm[128], colm[128];

    int bb = blockIdx.x;
    // XCD grouping: a batch's 8 tiles share one XCD (hw xcd = blockIdx % 8)
    int z = bb & 7, y = (bb >> 3) & 7, x = bb >> 6;
    int b  = z * 8 + x;
    int mt = y >> 2, nt = y & 3;           // mt 0..1, nt 0..3
    int m0 = mt * 128, n0 = nt * 128;

    const float* Vb = video + (size_t)b * VL * HD;
    const float* Tb = text  + (size_t)b * TL * HD;

    int tid = threadIdx.x;                 // 256 threads = 4 waves
    int l = tid & 63, wid = tid >> 6;
    int fr = l & 15, g = l >> 4;
    int wm = (wid >> 1) * 64, wn = (wid & 1) * 64;   // wave tile: 64 x 64

    // staging: thread stages 16 floats (2 chunks) of one A row and one B row
    int rS = tid >> 1;                     // row 0..127
    int c0 = (tid & 1) * 2;                // chunks c0, c0+1
    unsigned sw = (rS >> 1) & 3;
    unsigned w0 = rS * 16 + ((unsigned)c0       ^ sw) * 4;
    unsigned w1 = rS * 16 + ((unsigned)(c0 + 1) ^ sw) * 4;
    const float* aptr = Vb + (size_t)(m0 + rS) * HD + c0 * 8;
    const float* bptr = Tb + (size_t)(n0 + rS) * HD + c0 * 8;

    f32x4 acc[4][4];
#pragma unroll
    for (int i = 0; i < 4; ++i)
#pragma unroll
        for (int j = 0; j < 4; ++j) acc[i][j] = (f32x4){0.f, 0.f, 0.f, 0.f};

    float sa = 0.f, sb = 0.f;

    // prologue: stage step 0; prefetch step 1 raw
    float4 a0 = *(const float4*)(aptr),      a1 = *(const float4*)(aptr + 4);
    float4 a2 = *(const float4*)(aptr + 8),  a3 = *(const float4*)(aptr + 12);
    float4 b0 = *(const float4*)(bptr),      b1 = *(const float4*)(bptr + 4);
    float4 b2 = *(const float4*)(bptr + 8),  b3 = *(const float4*)(bptr + 12);
    cvt_store8(&pA[0][0][w0], &pA[0][1][w0], a0, a1, sa);
    cvt_store8(&pA[0][0][w1], &pA[0][1][w1], a2, a3, sa);
    cvt_store8(&pB[0][0][w0], &pB[0][1][w0], b0, b1, sb);
    cvt_store8(&pB[0][0][w1], &pB[0][1][w1], b2, b3, sb);
    a0 = *(const float4*)(aptr + 32); a1 = *(const float4*)(aptr + 36);
    a2 = *(const float4*)(aptr + 40); a3 = *(const float4*)(aptr + 44);
    b0 = *(const float4*)(bptr + 32); b1 = *(const float4*)(bptr + 36);
    b2 = *(const float4*)(bptr + 40); b3 = *(const float4*)(bptr + 44);
    __syncthreads();

    for (int t = 0; t < 16; ++t) {
        int cur = t & 1, nxt = cur ^ 1;
        short8 fah[4], fal[4], fbh[4], fbl[4];
#pragma unroll
        for (int i = 0; i < 4; ++i) {
            int row = wm + i * 16 + fr;
            unsigned ridx = row * 16 + (g ^ ((row >> 1) & 3)) * 4;
            fah[i] = *(const short8*)&pA[cur][0][ridx];
            fal[i] = *(const short8*)&pA[cur][1][ridx];
        }
#pragma unroll
        for (int j = 0; j < 4; ++j) {
            int row = wn + j * 16 + fr;
            unsigned ridx = row * 16 + (g ^ ((row >> 1) & 3)) * 4;
            fbh[j] = *(const short8*)&pB[cur][0][ridx];
            fbl[j] = *(const short8*)&pB[cur][1][ridx];
        }
        if (t < 15) {
            cvt_store8(&pA[nxt][0][w0], &pA[nxt][1][w0], a0, a1, sa);
            cvt_store8(&pA[nxt][0][w1], &pA[nxt][1][w1], a2, a3, sa);
            cvt_store8(&pB[nxt][0][w0], &pB[nxt][1][w0], b0, b1, sb);
            cvt_store8(&pB[nxt][0][w1], &pB[nxt][1][w1], b2, b3, sb);
            if (t < 14) {
                const float* ap = aptr + (t + 2) * 32;
                const float* bp = bptr + (t + 2) * 32;
                a0 = *(const float4*)ap;        a1 = *(const float4*)(ap + 4);
                a2 = *(const float4*)(ap + 8);  a3 = *(const float4*)(ap + 12);
                b0 = *(const float4*)bp;        b1 = *(const float4*)(bp + 4);
                b2 = *(const float4*)(bp + 8);  b3 = *(const float4*)(bp + 12);
            }
        }
        // 3 passes: 16 independent MFMAs between reuses of each acc
#pragma unroll
        for (int j = 0; j < 4; ++j)
#pragma unroll
            for (int i = 0; i < 4; ++i)
                acc[i][j] = __builtin_amdgcn_mfma_f32_16x16x32_bf16(fah[i], fbh[j], acc[i][j], 0, 0, 0);
#pragma unroll
        for (int j = 0; j < 4; ++j)
#pragma unroll
            for (int i = 0; i < 4; ++i)
                acc[i][j] = __builtin_amdgcn_mfma_f32_16x16x32_bf16(fal[i], fbh[j], acc[i][j], 0, 0, 0);
#pragma unroll
        for (int j = 0; j < 4; ++j)
#pragma unroll
            for (int i = 0; i < 4; ++i)
                acc[i][j] = __builtin_amdgcn_mfma_f32_16x16x32_bf16(fah[i], fbl[j], acc[i][j], 0, 0, 0);
        __syncthreads();
    }

    // fused norms: row rS's two 16-float halves live in lanes tid, tid^1
    sa += __shfl_xor(sa, 1, 64);
    sb += __shfl_xor(sb, 1, 64);
    if ((tid & 1) == 0) { vns_s[rS] = sqrtf(sa); tns_s[rS] = sqrtf(sb); }
    if (tid < 128) rowm[tid] = 0u;
    else           colm[tid - 128] = 0u;
    __syncthreads();

    // epilogue: cosine + row/col max.  C layout: col = lane&15 (N), row = g*4+reg (M)
    float vr[16], tc[4];
#pragma unroll
    for (int i = 0; i < 4; ++i)
#pragma unroll
        for (int r = 0; r < 4; ++r) vr[i * 4 + r] = vns_s[wm + i * 16 + g * 4 + r];
#pragma unroll
    for (int j = 0; j < 4; ++j) tc[j] = tns_s[wn + j * 16 + fr];

    float rmx[16], cmx[4];
#pragma unroll
    for (int i = 0; i < 16; ++i) rmx[i] = -INFINITY;
#pragma unroll
    for (int j = 0; j < 4; ++j) cmx[j] = -INFINITY;
#pragma unroll
    for (int i = 0; i < 4; ++i)
#pragma unroll
        for (int j = 0; j < 4; ++j)
#pragma unroll
            for (int r = 0; r < 4; ++r) {
                float s = acc[i][j][r] / fmaxf(vr[i * 4 + r] * tc[j], EPSF);
                rmx[i * 4 + r] = fmaxf(rmx[i * 4 + r], s);
                cmx[j]         = fmaxf(cmx[j], s);
            }
#pragma unroll
    for (int off = 1; off < 16; off <<= 1)
#pragma unroll
        for (int i = 0; i < 16; ++i) rmx[i] = fmaxf(rmx[i], __shfl_xor(rmx[i], off, 64));
#pragma unroll
    for (int off = 16; off < 64; off <<= 1)
#pragma unroll
        for (int j = 0; j < 4; ++j) cmx[j] = fmaxf(cmx[j], __shfl_xor(cmx[j], off, 64));
    if (fr == 0) {
#pragma unroll
        for (int i = 0; i < 4; ++i)
#pragma unroll
            for (int r = 0; r < 4; ++r)
                atomicMax(&rowm[wm + i * 16 + g * 4 + r], fkey(rmx[i * 4 + r]));
    }
    if (g == 0) {
#pragma unroll
        for (int j = 0; j < 4; ++j) atomicMax(&colm[wn + j * 16 + fr], fkey(cmx[j]));
    }
    __syncthreads();
    if (tid < 128) rowp[(b * 4 + nt) * VL + m0 + tid] = rowm[tid];
    else           colp[(b * 2 + mt) * TL + n0 + (tid - 128)] = colm[tid - 128];
}

// per-batch: combine partials, top-KV rows / top-KT cols (stable tie-break by index).
// Rank via uint4 broadcast scans; positions via wave ballot + popcount prefix.
__global__ __launch_bounds__(512) void k_select(const unsigned* __restrict__ rowp,
                                                const unsigned* __restrict__ colp,
                                                int* __restrict__ srcidx) {
    __shared__ __align__(16) unsigned rk[VL];
    __shared__ __align__(16) unsigned ck[TL];
    __shared__ int wsumv[4], wsumt[8];
    int b = blockIdx.x, tid = threadIdx.x;
    int lane = tid & 63, wv = tid >> 6;
    if (tid < VL) {
        unsigned m = max(max(rowp[(b * 4 + 0) * VL + tid], rowp[(b * 4 + 1) * VL + tid]),
                         max(rowp[(b * 4 + 2) * VL + tid], rowp[(b * 4 + 3) * VL + tid]));
        rk[tid] = m;
    }
    ck[tid] = max(colp[(b * 2 + 0) * TL + tid], colp[(b * 2 + 1) * TL + tid]);
    for (int i = tid; i < 768; i += 512) srcidx[b * 768 + i] = -1;
    __syncthreads();

    int flagv = 0;
    if (tid < VL) {
        unsigned me = rk[tid];
        int cnt = 0;
        for (int jb = 0; jb < VL / 4; ++jb) {
            uint4 k4 = *(const uint4*)&rk[jb * 4];
            cnt += (k4.x > me) + (k4.y > me) + (k4.z > me) + (k4.w > me);
            cnt += (k4.x == me && (jb * 4 + 0) < tid) + (k4.y == me && (jb * 4 + 1) < tid)
                 + (k4.z == me && (jb * 4 + 2) < tid) + (k4.w == me && (jb * 4 + 3) < tid);
        }
        flagv = (cnt < KV) ? 1 : 0;
    }
    int flagt;
    {
        unsigned me = ck[tid];
        int cnt = 0;
        for (int jb = 0; jb < TL / 4; ++jb) {
            uint4 k4 = *(const uint4*)&ck[jb * 4];
            cnt += (k4.x > me) + (k4.y > me) + (k4.z > me) + (k4.w > me);
            cnt += (k4.x == me && (jb * 4 + 0) < tid) + (k4.y == me && (jb * 4 + 1) < tid)
                 + (k4.z == me && (jb * 4 + 2) < tid) + (k4.w == me && (jb * 4 + 3) < tid);
        }
        flagt = (cnt < KT) ? 1 : 0;
    }

    unsigned long long mv = __ballot(flagv);
    unsigned long long mtk = __ballot(flagt);
    if (lane == 0) {
        if (wv < 4) wsumv[wv] = __popcll(mv);
        wsumt[wv] = __popcll(mtk);
    }
    __syncthreads();

    unsigned long long ltmask = (1ull << lane) - 1ull;
    if (tid < VL) {
        int base = 0;
#pragma unroll
        for (int w2 = 0; w2 < 4; ++w2) base += (w2 < wv) ? wsumv[w2] : 0;
        int mV = wsumv[0] + wsumv[1] + wsumv[2] + wsumv[3];
        int ps = base + __popcll(mv & ltmask);
        int pu = tid - ps;
        if (flagv) srcidx[b * 768 + ps] = tid;                              // v_mut
        else {
            int pos = pu - (KV - mV);                                       // skip first (KV-mV) unselected
            if (pos >= 0 && pos < VL - KV) srcidx[b * 768 + 382 + pos] = tid;  // v_only
        }
    }
    {
        int base = 0;
#pragma unroll
        for (int w2 = 0; w2 < 8; ++w2) base += (w2 < wv) ? wsumt[w2] : 0;
        int mT = 0;
#pragma unroll
        for (int w2 = 0; w2 < 8; ++w2) mT += wsumt[w2];
        int ps = base + __popcll(mtk & ltmask);
        int pu = tid - ps;
        if (flagt) srcidx[b * 768 + 127 + ps] = tid;                        // t_mut
        else {
            int pos = pu - (KT - mT);
            if (pos >= 0 && pos < TL - KT) srcidx[b * 768 + 511 + pos] = tid;  // t_only
        }
    }
}

// one wave per output row; out element offset == row*HD since segments concatenate in row order
__global__ __launch_bounds__(256) void k_gather(const float* __restrict__ video,
                                                const float* __restrict__ text,
                                                const int* __restrict__ srcidx,
                                                float* __restrict__ out) {
    int row  = blockIdx.x * 4 + (threadIdx.x >> 6);
    int lane = threadIdx.x & 63;
    int b, base, L;
    const float* tens;
    const int S0 = B_ * KV, S1 = S0 + B_ * KT, S2 = S1 + B_ * (VL - KV);
    if (row < S0)      { b = row / KV;            base = 0   + row % KV;            tens = video; L = VL; }
    else if (row < S1) { int r = row - S0; b = r / KT;       base = 127 + r % KT;       tens = text;  L = TL; }
    else if (row < S2) { int r = row - S1; b = r / (VL - KV); base = 382 + r % (VL - KV); tens = video; L = VL; }
    else               { int r = row - S2; b = r / (TL - KT); base = 511 + r % (TL - KT); tens = text;  L = TL; }
    int s = srcidx[b * 768 + base];
    float* op = out + (size_t)row * HD;
    if (s >= 0) {
        const float* sp = tens + ((size_t)b * L + s) * HD;
#pragma unroll
        for (int it = 0; it < 2; ++it) {
            f32x4 v = *(const f32x4*)(sp + lane * 4 + it * 256);
            __builtin_nontemporal_store(v, (f32x4*)(op + lane * 4 + it * 256));
        }
    } else {
        f32x4 zv = {0.f, 0.f, 0.f, 0.f};
#pragma unroll
        for (int it = 0; it < 2; ++it)
            __builtin_nontemporal_store(zv, (f32x4*)(op + lane * 4 + it * 256));
    }
}

extern "C" void kernel_launch(void* const* d_in, const int* in_sizes, int n_in,
                              void* d_out, int out_size, void* d_ws, size_t ws_size,
                              hipStream_t stream) {
    const float* video = (const float*)d_in[0];
    const float* text  = (const float*)d_in[1];
    float*    ws     = (float*)d_ws;
    unsigned* rowp   = (unsigned*)(ws + WS_ROWP);
    unsigned* colp   = (unsigned*)(ws + WS_COLP);
    int*      srcidx = (int*)(ws + WS_SRC);
    float*    out    = (float*)d_out;

    k_simmax<<<B_ * 8,          256, 0, stream>>>(video, text, rowp, colp);
    k_select<<<B_,              512, 0, stream>>>(rowp, colp, srcidx);
    k_gather<<<(B_ * 768) / 4,  256, 0, stream>>>(video, text, srcidx, out);
}